// Round 6
// baseline (104.817 us; speedup 1.0000x reference)
//
#include <hip/hip_runtime.h>

// out[n, lm, c] = node_feats[n,c] * sum_{e in seg(n)} edge_attrs[e,lm] * tp_weights[e, L[lm], c]
// L_OF_LM = [0, 1,1,1, 2,2,2,2,2, 3,3,3,3,3,3,3]
//
// Round 5 -> 6:
//  - edge_attrs scalar stream double-buffered (eaA/eaB in SGPRs) at the same
//    depth-2 schedule as the weights: removes the per-iteration
//    s_load -> lgkmcnt(0) -> FMA dependent stall
//  - bounds kernel: edge-parallel boundary scatter (O(1)/thread, ~400k
//    threads) instead of 25k-thread binary search (19 dependent loads each)
//  - unchanged: one wave/node, lane=channel, depth-2 weight pipeline,
//    nontemporal streaming, __launch_bounds__(256, 8)

#define FMA16A(EA, OFF, W0, W1, W2, W3)                                       \
    acc[0]  += EA[OFF + 0]  * W0;                                             \
    acc[1]  += EA[OFF + 1]  * W1;                                             \
    acc[2]  += EA[OFF + 2]  * W1;                                             \
    acc[3]  += EA[OFF + 3]  * W1;                                             \
    acc[4]  += EA[OFF + 4]  * W2;                                             \
    acc[5]  += EA[OFF + 5]  * W2;                                             \
    acc[6]  += EA[OFF + 6]  * W2;                                             \
    acc[7]  += EA[OFF + 7]  * W2;                                             \
    acc[8]  += EA[OFF + 8]  * W2;                                             \
    acc[9]  += EA[OFF + 9]  * W3;                                             \
    acc[10] += EA[OFF + 10] * W3;                                             \
    acc[11] += EA[OFF + 11] * W3;                                             \
    acc[12] += EA[OFF + 12] * W3;                                             \
    acc[13] += EA[OFF + 13] * W3;                                             \
    acc[14] += EA[OFF + 14] * W3;                                             \
    acc[15] += EA[OFF + 15] * W3;

#define FMA32(EA, W)                                                          \
    FMA16A(EA, 0,  W[0], W[1], W[2], W[3])                                    \
    FMA16A(EA, 16, W[4], W[5], W[6], W[7])

#define LOAD_W8(DST, EBASE)                                                   \
    {                                                                         \
        const float* wp = tp_weights + (size_t)(EBASE) * 256 + lane;          \
        DST[0] = __builtin_nontemporal_load(wp);                              \
        DST[1] = __builtin_nontemporal_load(wp + 64);                         \
        DST[2] = __builtin_nontemporal_load(wp + 128);                        \
        DST[3] = __builtin_nontemporal_load(wp + 192);                        \
        DST[4] = __builtin_nontemporal_load(wp + 256);                        \
        DST[5] = __builtin_nontemporal_load(wp + 320);                        \
        DST[6] = __builtin_nontemporal_load(wp + 384);                        \
        DST[7] = __builtin_nontemporal_load(wp + 448);                        \
    }

#define LOAD_EA(DST, EBASE)                                                   \
    {                                                                         \
        const float* eap = edge_attrs + (size_t)(EBASE) * 16;                 \
        _Pragma("unroll")                                                     \
        for (int i = 0; i < 32; ++i) DST[i] = eap[i];                         \
    }

// Edge-parallel bounds: thread e owns receivers in (recv[e], recv[e+1]];
// off[n] = lower_bound(recv, n). Disjoint ranges -> no races.
__global__ __launch_bounds__(256) void bounds_scatter(
    const int* __restrict__ recv, int nedges, int nnodes,
    int* __restrict__ off)
{
    const int e = blockIdx.x * blockDim.x + threadIdx.x;
    if (e >= nedges) return;
    const int r  = recv[e];
    const int rn = (e + 1 < nedges) ? recv[e + 1] : nnodes;
    if (e == 0)
        for (int n = 0; n <= r; ++n) off[n] = 0;
    for (int n = r + 1; n <= rn; ++n) off[n] = e + 1;
}

__global__ __launch_bounds__(256, 8) void imp_tp_main(
    const float* __restrict__ node_feats,   // [nnodes][64]
    const float* __restrict__ edge_attrs,   // [nedges][16]
    const float* __restrict__ tp_weights,   // [nedges][4][64]
    const int*   __restrict__ off,          // [nnodes+1]
    int nnodes,
    float* __restrict__ out)                // [nnodes][16][64]
{
    const int wave = (blockIdx.x * blockDim.x + threadIdx.x) >> 6;
    const int lane = threadIdx.x & 63;
    if (wave >= nnodes) return;
    const int n = wave;

    const int start = __builtin_amdgcn_readfirstlane(off[n]);
    const int end   = __builtin_amdgcn_readfirstlane(off[n + 1]);

    const float nf = node_feats[(size_t)n * 64 + lane];

    float acc[16];
    #pragma unroll
    for (int i = 0; i < 16; ++i) acc[i] = 0.f;

    const int npairs = (end - start) >> 1;
    int e = start;
    float wa[8], wb[8];
    float eaA[32], eaB[32];

    if (npairs > 0) { LOAD_W8(wa, e)     LOAD_EA(eaA, e) }
    if (npairs > 1) { LOAD_W8(wb, e + 2) LOAD_EA(eaB, e + 2) }

    int p = 0;
    // steady state: consume pair p (wa/eaA), p+1 (wb/eaB); prefetch p+2, p+3
    for (; p + 3 < npairs; p += 2, e += 4) {
        FMA32(eaA, wa)
        LOAD_W8(wa, e + 4) LOAD_EA(eaA, e + 4)
        FMA32(eaB, wb)
        LOAD_W8(wb, e + 6) LOAD_EA(eaB, e + 6)
    }
    const int r = npairs - p;
    if (r == 3) {
        FMA32(eaA, wa)
        LOAD_W8(wa, e + 4) LOAD_EA(eaA, e + 4)
        FMA32(eaB, wb)
        FMA32(eaA, wa)
        e += 6;
    } else if (r == 2) {
        FMA32(eaA, wa)
        FMA32(eaB, wb)
        e += 4;
    } else if (r == 1) {
        FMA32(eaA, wa)
        e += 2;
    }
    if (e < end) {   // odd tail edge
        const float* wp = tp_weights + (size_t)e * 256 + lane;
        const float a0 = __builtin_nontemporal_load(wp);
        const float a1 = __builtin_nontemporal_load(wp + 64);
        const float a2 = __builtin_nontemporal_load(wp + 128);
        const float a3 = __builtin_nontemporal_load(wp + 192);
        float ea[16];
        const float* eap = edge_attrs + (size_t)e * 16;
        #pragma unroll
        for (int i = 0; i < 16; ++i) ea[i] = eap[i];
        FMA16A(ea, 0, a0, a1, a2, a3)
    }

    float* o = out + (size_t)n * 1024 + lane;
    #pragma unroll
    for (int lm = 0; lm < 16; ++lm)
        __builtin_nontemporal_store(acc[lm] * nf, o + lm * 64);
}

// Fallback (ws too small): in-wave binary search, known-correct from round 1.
__global__ __launch_bounds__(256) void imp_tp_fallback(
    const float* __restrict__ node_feats,
    const float* __restrict__ edge_attrs,
    const float* __restrict__ tp_weights,
    const int*   __restrict__ recv,
    int nnodes, int nedges,
    float* __restrict__ out)
{
    const int wave = (blockIdx.x * blockDim.x + threadIdx.x) >> 6;
    const int lane = threadIdx.x & 63;
    if (wave >= nnodes) return;
    const int n = wave;

    int lo = 0, hi = nedges;
    while (lo < hi) { int mid = (lo + hi) >> 1; if (recv[mid] < n) lo = mid + 1; else hi = mid; }
    const int start = lo;
    hi = nedges;
    while (lo < hi) { int mid = (lo + hi) >> 1; if (recv[mid] < n + 1) lo = mid + 1; else hi = mid; }
    const int end = lo;

    float acc[16];
    #pragma unroll
    for (int i = 0; i < 16; ++i) acc[i] = 0.f;

    for (int e = start; e < end; ++e) {
        const float4* ea4 = reinterpret_cast<const float4*>(edge_attrs + (size_t)e * 16);
        const float4 ea0 = ea4[0];
        const float4 ea1 = ea4[1];
        const float4 ea2 = ea4[2];
        const float4 ea3 = ea4[3];
        const float* w = tp_weights + (size_t)e * 256 + lane;
        const float w0 = w[0];
        const float w1 = w[64];
        const float w2 = w[128];
        const float w3 = w[192];

        acc[0]  += ea0.x * w0;
        acc[1]  += ea0.y * w1;
        acc[2]  += ea0.z * w1;
        acc[3]  += ea0.w * w1;
        acc[4]  += ea1.x * w2;
        acc[5]  += ea1.y * w2;
        acc[6]  += ea1.z * w2;
        acc[7]  += ea1.w * w2;
        acc[8]  += ea2.x * w2;
        acc[9]  += ea2.y * w3;
        acc[10] += ea2.z * w3;
        acc[11] += ea2.w * w3;
        acc[12] += ea3.x * w3;
        acc[13] += ea3.y * w3;
        acc[14] += ea3.z * w3;
        acc[15] += ea3.w * w3;
    }

    const float nf = node_feats[(size_t)n * 64 + lane];
    float* o = out + (size_t)n * 1024 + lane;
    #pragma unroll
    for (int lm = 0; lm < 16; ++lm) o[lm * 64] = acc[lm] * nf;
}

extern "C" void kernel_launch(void* const* d_in, const int* in_sizes, int n_in,
                              void* d_out, int out_size, void* d_ws, size_t ws_size,
                              hipStream_t stream) {
    const float* node_feats = (const float*)d_in[0];
    const float* edge_attrs = (const float*)d_in[1];
    const float* tp_weights = (const float*)d_in[2];
    const int*   recv       = (const int*)d_in[3];
    float* out = (float*)d_out;

    const int nnodes = in_sizes[0] / 64;
    const int nedges = in_sizes[1] / 16;

    const int threads = 256;  // 4 waves/block
    const int blocks = (nnodes * 64 + threads - 1) / threads;

    if (ws_size >= (size_t)(nnodes + 1) * sizeof(int)) {
        int* off = (int*)d_ws;
        const int bthreads = 256;
        const int bblocks = (nedges + bthreads - 1) / bthreads;
        bounds_scatter<<<bblocks, bthreads, 0, stream>>>(recv, nedges, nnodes, off);
        imp_tp_main<<<blocks, threads, 0, stream>>>(
            node_feats, edge_attrs, tp_weights, off, nnodes, out);
    } else {
        imp_tp_fallback<<<blocks, threads, 0, stream>>>(
            node_feats, edge_attrs, tp_weights, recv, nnodes, nedges, out);
    }
}

// Round 7
// 101.063 us; speedup vs baseline: 1.0372x; 1.0372x over previous
//
#include <hip/hip_runtime.h>

// out[n, lm, c] = node_feats[n,c] * sum_{e in seg(n)} edge_attrs[e,lm] * tp_weights[e, L[lm], c]
// L_OF_LM = [0, 1,1,1, 2,2,2,2,2, 3,3,3,3,3,3,3]
//
// Round 6 -> 7 (best-of + latency-exposure cleanup):
//  - base = round-4 config (best measured): depth-1 weight pipeline, scalar-path
//    edge_attrs (uniform e), nontemporal streams, __launch_bounds__(256)
//  - bounds kernel: edge-parallel O(1)/thread scatter (isolated this time;
//    round-6 bundled it with the harmful ea-dbuf)
//  - odd-degree nodes: process the odd edge FIRST with its loads issued in the
//    prologue ahead of the first pair's loads -> its ~900cy HBM latency
//    overlaps the pipeline fill instead of being an exposed tail stall

#define FMA16(EA, W0, W1, W2, W3)                                             \
    acc[0]  += EA[0]  * W0;                                                   \
    acc[1]  += EA[1]  * W1;                                                   \
    acc[2]  += EA[2]  * W1;                                                   \
    acc[3]  += EA[3]  * W1;                                                   \
    acc[4]  += EA[4]  * W2;                                                   \
    acc[5]  += EA[5]  * W2;                                                   \
    acc[6]  += EA[6]  * W2;                                                   \
    acc[7]  += EA[7]  * W2;                                                   \
    acc[8]  += EA[8]  * W2;                                                   \
    acc[9]  += EA[9]  * W3;                                                   \
    acc[10] += EA[10] * W3;                                                   \
    acc[11] += EA[11] * W3;                                                   \
    acc[12] += EA[12] * W3;                                                   \
    acc[13] += EA[13] * W3;                                                   \
    acc[14] += EA[14] * W3;                                                   \
    acc[15] += EA[15] * W3;

#define LOAD_W8(DST, EBASE)                                                   \
    {                                                                         \
        const float* wp = tp_weights + (size_t)(EBASE) * 256 + lane;          \
        DST[0] = __builtin_nontemporal_load(wp);                              \
        DST[1] = __builtin_nontemporal_load(wp + 64);                         \
        DST[2] = __builtin_nontemporal_load(wp + 128);                        \
        DST[3] = __builtin_nontemporal_load(wp + 192);                        \
        DST[4] = __builtin_nontemporal_load(wp + 256);                        \
        DST[5] = __builtin_nontemporal_load(wp + 320);                        \
        DST[6] = __builtin_nontemporal_load(wp + 384);                        \
        DST[7] = __builtin_nontemporal_load(wp + 448);                        \
    }

#define LOAD_W4(DST, EBASE)                                                   \
    {                                                                         \
        const float* wp = tp_weights + (size_t)(EBASE) * 256 + lane;          \
        DST[0] = __builtin_nontemporal_load(wp);                              \
        DST[1] = __builtin_nontemporal_load(wp + 64);                         \
        DST[2] = __builtin_nontemporal_load(wp + 128);                        \
        DST[3] = __builtin_nontemporal_load(wp + 192);                        \
    }

// Edge-parallel bounds: thread e owns receivers in (recv[e], recv[e+1]];
// off[n] = lower_bound(recv, n). Disjoint ranges -> no races.
__global__ __launch_bounds__(256) void bounds_scatter(
    const int* __restrict__ recv, int nedges, int nnodes,
    int* __restrict__ off)
{
    const int e = blockIdx.x * blockDim.x + threadIdx.x;
    if (e >= nedges) return;
    const int r  = recv[e];
    const int rn = (e + 1 < nedges) ? recv[e + 1] : nnodes;
    if (e == 0)
        for (int n = 0; n <= r; ++n) off[n] = 0;
    for (int n = r + 1; n <= rn; ++n) off[n] = e + 1;
}

__global__ __launch_bounds__(256) void imp_tp_main(
    const float* __restrict__ node_feats,   // [nnodes][64]
    const float* __restrict__ edge_attrs,   // [nedges][16]
    const float* __restrict__ tp_weights,   // [nedges][4][64]
    const int*   __restrict__ off,          // [nnodes+1]
    int nnodes,
    float* __restrict__ out)                // [nnodes][16][64]
{
    const int wave = (blockIdx.x * blockDim.x + threadIdx.x) >> 6;
    const int lane = threadIdx.x & 63;
    if (wave >= nnodes) return;
    const int n = wave;

    const int start = __builtin_amdgcn_readfirstlane(off[n]);
    const int end   = __builtin_amdgcn_readfirstlane(off[n + 1]);

    const float nf = node_feats[(size_t)n * 64 + lane];

    float acc[16];
    #pragma unroll
    for (int i = 0; i < 16; ++i) acc[i] = 0.f;

    const int deg    = end - start;
    const int odd    = deg & 1;
    const int npairs = deg >> 1;
    int e = start;

    float wo[4];
    float w[8];
    // issue odd-edge loads FIRST, then the first pair's -> counted vmcnt lets
    // the odd-edge FMAs proceed while the pair loads stay in flight
    if (odd)        LOAD_W4(wo, e)
    if (npairs > 0) LOAD_W8(w, e + odd)

    if (odd) {
        const float* eap = edge_attrs + (size_t)e * 16;
        float ea[16];
        #pragma unroll
        for (int i = 0; i < 16; ++i) ea[i] = eap[i];
        FMA16(ea, wo[0], wo[1], wo[2], wo[3])
        e += 1;
    }

    // steady state: prefetch pair p+1, compute pair p (depth-1, round-4 best)
    for (int p = 0; p + 1 < npairs; ++p, e += 2) {
        float wn[8];
        LOAD_W8(wn, e + 2)
        const float* eap = edge_attrs + (size_t)e * 16;   // uniform -> s_load
        float ea[32];
        #pragma unroll
        for (int i = 0; i < 32; ++i) ea[i] = eap[i];
        FMA16(ea, w[0], w[1], w[2], w[3])
        FMA16((ea + 16), w[4], w[5], w[6], w[7])
        #pragma unroll
        for (int i = 0; i < 8; ++i) w[i] = wn[i];
    }
    if (npairs > 0) {
        const float* eap = edge_attrs + (size_t)e * 16;
        float ea[32];
        #pragma unroll
        for (int i = 0; i < 32; ++i) ea[i] = eap[i];
        FMA16(ea, w[0], w[1], w[2], w[3])
        FMA16((ea + 16), w[4], w[5], w[6], w[7])
        e += 2;
    }

    float* o = out + (size_t)n * 1024 + lane;
    #pragma unroll
    for (int lm = 0; lm < 16; ++lm)
        __builtin_nontemporal_store(acc[lm] * nf, o + lm * 64);
}

// Fallback (ws too small): in-wave binary search, known-correct from round 1.
__global__ __launch_bounds__(256) void imp_tp_fallback(
    const float* __restrict__ node_feats,
    const float* __restrict__ edge_attrs,
    const float* __restrict__ tp_weights,
    const int*   __restrict__ recv,
    int nnodes, int nedges,
    float* __restrict__ out)
{
    const int wave = (blockIdx.x * blockDim.x + threadIdx.x) >> 6;
    const int lane = threadIdx.x & 63;
    if (wave >= nnodes) return;
    const int n = wave;

    int lo = 0, hi = nedges;
    while (lo < hi) { int mid = (lo + hi) >> 1; if (recv[mid] < n) lo = mid + 1; else hi = mid; }
    const int start = lo;
    hi = nedges;
    while (lo < hi) { int mid = (lo + hi) >> 1; if (recv[mid] < n + 1) lo = mid + 1; else hi = mid; }
    const int end = lo;

    float acc[16];
    #pragma unroll
    for (int i = 0; i < 16; ++i) acc[i] = 0.f;

    for (int e = start; e < end; ++e) {
        const float4* ea4 = reinterpret_cast<const float4*>(edge_attrs + (size_t)e * 16);
        const float4 ea0 = ea4[0];
        const float4 ea1 = ea4[1];
        const float4 ea2 = ea4[2];
        const float4 ea3 = ea4[3];
        const float* w = tp_weights + (size_t)e * 256 + lane;
        const float w0 = w[0];
        const float w1 = w[64];
        const float w2 = w[128];
        const float w3 = w[192];

        acc[0]  += ea0.x * w0;
        acc[1]  += ea0.y * w1;
        acc[2]  += ea0.z * w1;
        acc[3]  += ea0.w * w1;
        acc[4]  += ea1.x * w2;
        acc[5]  += ea1.y * w2;
        acc[6]  += ea1.z * w2;
        acc[7]  += ea1.w * w2;
        acc[8]  += ea2.x * w2;
        acc[9]  += ea2.y * w3;
        acc[10] += ea2.z * w3;
        acc[11] += ea2.w * w3;
        acc[12] += ea3.x * w3;
        acc[13] += ea3.y * w3;
        acc[14] += ea3.z * w3;
        acc[15] += ea3.w * w3;
    }

    const float nf = node_feats[(size_t)n * 64 + lane];
    float* o = out + (size_t)n * 1024 + lane;
    #pragma unroll
    for (int lm = 0; lm < 16; ++lm) o[lm * 64] = acc[lm] * nf;
}

extern "C" void kernel_launch(void* const* d_in, const int* in_sizes, int n_in,
                              void* d_out, int out_size, void* d_ws, size_t ws_size,
                              hipStream_t stream) {
    const float* node_feats = (const float*)d_in[0];
    const float* edge_attrs = (const float*)d_in[1];
    const float* tp_weights = (const float*)d_in[2];
    const int*   recv       = (const int*)d_in[3];
    float* out = (float*)d_out;

    const int nnodes = in_sizes[0] / 64;
    const int nedges = in_sizes[1] / 16;

    const int threads = 256;  // 4 waves/block
    const int blocks = (nnodes * 64 + threads - 1) / threads;

    if (ws_size >= (size_t)(nnodes + 1) * sizeof(int)) {
        int* off = (int*)d_ws;
        const int bthreads = 256;
        const int bblocks = (nedges + bthreads - 1) / bthreads;
        bounds_scatter<<<bblocks, bthreads, 0, stream>>>(recv, nedges, nnodes, off);
        imp_tp_main<<<blocks, threads, 0, stream>>>(
            node_feats, edge_attrs, tp_weights, off, nnodes, out);
    } else {
        imp_tp_fallback<<<blocks, threads, 0, stream>>>(
            node_feats, edge_attrs, tp_weights, recv, nnodes, nedges, out);
    }
}